// Round 12
// baseline (383.683 us; speedup 1.0000x reference)
//
#include <hip/hip_runtime.h>
#include <hip/hip_bf16.h>
#include <math.h>

// MotionNet: PointNet++-style 2-level SA.  B=32, L=16, N=512.
// M = B*npoint*nsample = 131072 for all four conv layers.
//
// R12: R11 (373.9 µs) + coalesced conv-Y epilogue.  The direct D-fragment
// store put consecutive lanes at stride 2*O bytes (64 cache lines per store
// => ~16x L2 write-transaction amplification; convs sat at ~5% on every
// pipe).  Y now goes through an LDS transpose (two 32-row halves, stride
// O+10 breaks pow-2 banking, buffer aliases xs) and streams out as
// contiguous 16B/lane stores.  Values bit-identical; only the store path
// changes.  (This epilogue was validated correct in R8; R8's regression was
// the atomic BN stats committed alongside it.)
// Everything else byte-identical to R11.

#define BATCH 32
#define MCOLS 131072
#define CGRID 2048            // MCOLS / 64 conv blocks

typedef __attribute__((ext_vector_type(8))) short short8;
typedef __attribute__((ext_vector_type(4))) short short4v;
typedef __attribute__((ext_vector_type(4))) float f32x4;

__device__ __forceinline__ float b2f(short s) {
    return __uint_as_float(((unsigned)(unsigned short)s) << 16);
}
__device__ __forceinline__ short f2b(float f) {
    __hip_bfloat16 h = __float2bfloat16(f);
    return (short)__builtin_bit_cast(unsigned short, h);
}
__device__ __forceinline__ float dpp_row16_sum(float v) {
    int x;
    x = __builtin_amdgcn_update_dpp(0, __float_as_int(v), 0x111, 0xf, 0xf, true);
    v += __int_as_float(x);
    x = __builtin_amdgcn_update_dpp(0, __float_as_int(v), 0x112, 0xf, 0xf, true);
    v += __int_as_float(x);
    x = __builtin_amdgcn_update_dpp(0, __float_as_int(v), 0x114, 0xf, 0xf, true);
    v += __int_as_float(x);
    x = __builtin_amdgcn_update_dpp(0, __float_as_int(v), 0x118, 0xf, 0xf, true);
    v += __int_as_float(x);
    return v;
}
template<int C>
__device__ __forceinline__ float dpp_max(float v) {
    int x = __builtin_amdgcn_update_dpp(0, __float_as_int(v), C, 0xf, 0xf, true);
    return fmaxf(v, __int_as_float(x));
}
__device__ __forceinline__ float readlane_f(float v, int lane) {
    return __int_as_float(__builtin_amdgcn_readlane(__float_as_int(v), lane));
}

// ---------------------------------------------------------------- setup
__device__ __forceinline__ void prep_elem(const float* __restrict__ w, int O, int C,
                                          int CK, short* __restrict__ hi,
                                          short* __restrict__ lo, int t) {
    if (t >= O * CK) return;
    int o = t / CK, c = t % CK;
    float f = (c < C) ? w[o * C + c] : 0.f;
    short h = f2b(f);
    float fh = b2f(h);
    int NT = O >> 4;
    int ot = o >> 4, l15 = o & 15;
    int kc = c >> 5, quad = (c & 31) >> 3, j = c & 7;
    size_t idx = (((size_t)kc * NT + ot) * 64 + quad * 16 + l15) * 8 + j;
    hi[idx] = h;
    lo[idx] = f2b(f - fh);
}

__device__ __forceinline__ void shift_elem(const float* __restrict__ xyz,
                                           float* __restrict__ qout, int t, int N) {
    int c = t % 3;
    int n = (t / 3) % N;
    int b = t / (3 * N);
    int l = b & 15;
    float v;
    if (l < 15) {
        v = xyz[((size_t)(b + 1) * N + n) * 3 + c];
    } else {
        int g0 = b - 15;
        float acc = 0.f;
        for (int i = 0; i < 15; ++i) {
            float d = __fsub_rn(xyz[((size_t)(g0 + i + 1) * N + n) * 3 + c],
                                xyz[((size_t)(g0 + i) * N + n) * 3 + c]);
            acc = __fadd_rn(acc, d);
        }
        v = __fadd_rn(xyz[((size_t)b * N + n) * 3 + c], __fdiv_rn(acc, 15.f));
    }
    qout[t] = v;
}

// 432 blocks: [0,32) w1b, [32,112) w2a, [112,240) w2b, [240,432) shift1
__global__ __launch_bounds__(256) void setup_kernel(
        const float* __restrict__ w1b, const float* __restrict__ w2a,
        const float* __restrict__ w2b,
        const float* __restrict__ xyz, float* __restrict__ qs1,
        short* w1bH, short* w1bL,
        short* w2aH, short* w2aL, short* w2bH, short* w2bL) {
    int bid = blockIdx.x;
    int tid = threadIdx.x;
    if (bid < 32)       prep_elem(w1b, 128, 64, 64,   w1bH, w1bL, bid * 256 + tid);
    else if (bid < 112) prep_elem(w2a, 128, 131, 160, w2aH, w2aL, (bid - 32) * 256 + tid);
    else if (bid < 240) prep_elem(w2b, 256, 128, 128, w2bH, w2bL, (bid - 112) * 256 + tid);
    else {
        int t = (bid - 240) * 256 + tid;
        if (t < BATCH * 512 * 3) shift_elem(xyz, qs1, t, 512);
    }
}

// ---------------------------------------------------------------- FPS spine
template<int N, int NPOINT>
__device__ __forceinline__ void fps_spine(const float4* __restrict__ qp,
                                          int* __restrict__ sel, int lane) {
    constexpr int P = N / 64;
    float px[P], py[P], pz[P], mind[P];
#pragma unroll
    for (int p = 0; p < P; ++p) {
        float4 v = qp[lane * P + p];
        px[p] = v.x; py[p] = v.y; pz[p] = v.z;
        mind[p] = 1e10f;
    }
    float4 L0 = qp[0];
    float lx = L0.x, ly = L0.y, lz = L0.z;
    for (int s = 1; s < NPOINT; ++s) {
        float mn[P];
#pragma unroll
        for (int p = 0; p < P; ++p) {
            float dx = __fsub_rn(px[p], lx);
            float dy = __fsub_rn(py[p], ly);
            float dz = __fsub_rn(pz[p], lz);
            float d = __fadd_rn(__fadd_rn(__fmul_rn(dx, dx), __fmul_rn(dy, dy)),
                                __fmul_rn(dz, dz));
            float m2 = fminf(mind[p], d);
            mind[p] = m2;
            mn[p] = m2;
        }
        float t[P];
#pragma unroll
        for (int p = 0; p < P; ++p) t[p] = mn[p];
#pragma unroll
        for (int w = P / 2; w >= 1; w >>= 1)
#pragma unroll
            for (int p = 0; p < w; ++p) t[p] = fmaxf(t[p], t[p + w]);
        float local = t[0];
        float m = local;
        m = dpp_max<0x111>(m);
        m = dpp_max<0x112>(m);
        m = dpp_max<0x114>(m);
        m = dpp_max<0x118>(m);
        m = dpp_max<0x142>(m);
        m = dpp_max<0x143>(m);
        float maxd = readlane_f(m, 63);
        int enc = P - 1;
        float bx = px[P - 1], by = py[P - 1], bz = pz[P - 1];
#pragma unroll
        for (int p = P - 2; p >= 0; --p) {
            bool e = (mn[p] == local);
            enc = e ? p : enc;
            bx = e ? px[p] : bx;
            by = e ? py[p] : by;
            bz = e ? pz[p] : bz;
        }
        unsigned long long msk = __ballot(local == maxd);
        int winner = (int)__builtin_ctzll(msk);
        int last = winner * P + __builtin_amdgcn_readlane(enc, winner);
        lx = readlane_f(bx, winner);
        ly = readlane_f(by, winner);
        lz = readlane_f(bz, winner);
        if (lane == 0) sel[s] = last;
    }
}

// Standalone single-wave FPS (fps1).
template<int N, int NPOINT>
__global__ __launch_bounds__(64) void fps_kernel(const float* __restrict__ q,
                                                 float* __restrict__ qsel) {
    int b = blockIdx.x;
    int lane = threadIdx.x;
    __shared__ float4 qp[N];
    __shared__ int sel[NPOINT];
    const float* qb = q + (size_t)b * N * 3;
    for (int j = lane; j < N; j += 64)
        qp[j] = make_float4(qb[j * 3 + 0], qb[j * 3 + 1], qb[j * 3 + 2], 0.f);
    if (lane == 0) sel[0] = 0;
    __syncthreads();
    fps_spine<N, NPOINT>(qp, sel, lane);
    __syncthreads();
    for (int i = lane; i < NPOINT; i += 64) {
        float4 Pt = qp[sel[i]];
        size_t o = ((size_t)b * NPOINT + i) * 3;
        qsel[o + 0] = Pt.x;
        qsel[o + 1] = Pt.y;
        qsel[o + 2] = Pt.z;
    }
}

// 256-thread fps body (fused into conv1b's grid); wave 0 runs the spine.
__device__ void fps256_body(const float* __restrict__ q, float* __restrict__ qsel,
                            int b, char* smem) {
    constexpr int N = 256, NPOINT = 128;
    float4* qp = (float4*)smem;              // 4096 B
    int* sel = (int*)(smem + N * 16);        // 512 B
    int tid = threadIdx.x;
    const float* qb = q + (size_t)b * N * 3;
    for (int j = tid; j < N; j += 256)
        qp[j] = make_float4(qb[j * 3 + 0], qb[j * 3 + 1], qb[j * 3 + 2], 0.f);
    if (tid == 0) sel[0] = 0;
    __syncthreads();
    if (tid < 64) fps_spine<N, NPOINT>(qp, sel, tid);
    __syncthreads();
    for (int i = tid; i < NPOINT; i += 256) {
        float4 Pt = qp[sel[i]];
        size_t o = ((size_t)b * NPOINT + i) * 3;
        qsel[o + 0] = Pt.x;
        qsel[o + 1] = Pt.y;
        qsel[o + 2] = Pt.z;
    }
}

// ---------------------------------------------------------------- ballq1+conv1a
template<int N, int NPOINT, int NS>
__global__ __launch_bounds__(256) void ballq1_conv(
        const float* __restrict__ xyz,    // (B,N,3)
        const float* __restrict__ qpts,   // (B,NPOINT,3)
        const float* __restrict__ w1a,    // (64,6) f32
        float r2, float radius,
        short* __restrict__ Y, float* __restrict__ gate,
        float* __restrict__ pS, float* __restrict__ pS2) {
    static_assert((NS & (NS - 1)) == 0, "NS pow2");
    constexpr int O = 64;
    int tid = threadIdx.x;
    int lane = tid & 63;
    int wib = tid >> 6;
    int wid = blockIdx.x * 4 + wib;
    int b = wid / NPOINT;
    int i = wid % NPOINT;
    const float* qp = qpts + ((size_t)b * NPOINT + i) * 3;
    float qx = qp[0], qy = qp[1], qz = qp[2];
    __shared__ int gsh[4][NS];
    __shared__ float xsh[4][NS][6];
    __shared__ float wsh[O * 6];
    __shared__ float sblk[4][O], s2blk[4][O];
    for (int k = tid; k < O * 6; k += 256) wsh[k] = w1a[k];
    int* gidx = gsh[wib];
    int taken = 0, first = 0;
    bool any = false;
#pragma unroll
    for (int base = 0; base < N; base += 64) {
        int j = base + lane;
        const float* p = xyz + ((size_t)b * N + j) * 3;
        float dx = __fsub_rn(qx, p[0]);
        float dy = __fsub_rn(qy, p[1]);
        float dz = __fsub_rn(qz, p[2]);
        float d2 = __fadd_rn(__fadd_rn(__fmul_rn(dx, dx), __fmul_rn(dy, dy)),
                             __fmul_rn(dz, dz));
        bool in = d2 < r2;
        unsigned long long mk = __ballot(in);
        if (!any && mk) { first = base + __builtin_ctzll(mk); any = true; }
        int cb = __builtin_popcountll(mk & ((1ull << lane) - 1ull));
        int slot = taken + cb;
        if (in && slot < NS) gidx[slot] = j;
        taken += (int)__builtin_popcountll(mk);
    }
    if (taken < NS) {
        for (int s = taken + lane; s < NS; s += 64) gidx[s] = any ? first : 0;
    }
    __syncthreads();   // gidx + wsh visible
    int m0 = wid * NS;
    if (lane < NS) {
        int g = gidx[lane];
        const float* p = xyz + ((size_t)b * N + g) * 3;
        float dx = (p[0] - qx) / radius;
        float dy = (p[1] - qy) / radius;
        float dz = (p[2] - qz) / radius;
        float dist = sqrtf(dx * dx + dy * dy + dz * dz);
        gate[m0 + lane] = 1.f / (1.f + expf(-dist));
        xsh[wib][lane][0] = dx;
        xsh[wib][lane][1] = dy;
        xsh[wib][lane][2] = dz;
        xsh[wib][lane][3] = p[0];
        xsh[wib][lane][4] = p[1];
        xsh[wib][lane][5] = p[2];
    }
    __syncthreads();   // xsh visible (uniform barrier)
    float w0 = wsh[lane * 6 + 0], w1 = wsh[lane * 6 + 1], w2 = wsh[lane * 6 + 2];
    float w3 = wsh[lane * 6 + 3], w4 = wsh[lane * 6 + 4], w5 = wsh[lane * 6 + 5];
    float sum = 0.f, sum2 = 0.f;
#pragma unroll
    for (int s = 0; s < NS; ++s) {
        const float* x = xsh[wib][s];
        float y = fmaf(x[5], w5, fmaf(x[4], w4, fmaf(x[3], w3,
                  fmaf(x[2], w2, fmaf(x[1], w1, x[0] * w0)))));
        Y[(size_t)(m0 + s) * O + lane] = f2b(y);
        sum += y;
        sum2 = fmaf(y, y, sum2);
    }
    sblk[wib][lane] = sum;
    s2blk[wib][lane] = sum2;
    __syncthreads();
    if (tid < O) {
        float S  = sblk[0][tid] + sblk[1][tid] + sblk[2][tid] + sblk[3][tid];
        float S2 = s2blk[0][tid] + s2blk[1][tid] + s2blk[2][tid] + s2blk[3][tid];
        pS [(size_t)tid * CGRID + blockIdx.x] = S;
        pS2[(size_t)tid * CGRID + blockIdx.x] = S2;
    }
}

// ---------------------------------------------------------------- ball query (module 2)
template<int N, int NPOINT, int NS, int CF, int CK>
__global__ __launch_bounds__(256) void ballq_kernel(
        const float* __restrict__ xyz,    // (B,N,3)
        const float* __restrict__ qpts,   // (B,NPOINT,3)
        const float* __restrict__ feats,  // (B,N,CF)
        float r2, float radius,
        short* __restrict__ X, float* __restrict__ gate) {
    static_assert((NS & (NS - 1)) == 0, "NS pow2");
    static_assert(CK % 8 == 0, "CK mult of 8");
    int lane = threadIdx.x & 63;
    int wib = threadIdx.x >> 6;
    int wid = blockIdx.x * 4 + wib;
    int b = wid / NPOINT;
    int i = wid % NPOINT;
    const float* qp = qpts + ((size_t)b * NPOINT + i) * 3;
    float qx = qp[0], qy = qp[1], qz = qp[2];
    __shared__ int gsh[4][NS];
    int* gidx = gsh[wib];
    int taken = 0, first = 0;
    bool any = false;
#pragma unroll
    for (int base = 0; base < N; base += 64) {
        int j = base + lane;
        const float* p = xyz + ((size_t)b * N + j) * 3;
        float dx = __fsub_rn(qx, p[0]);
        float dy = __fsub_rn(qy, p[1]);
        float dz = __fsub_rn(qz, p[2]);
        float d2 = __fadd_rn(__fadd_rn(__fmul_rn(dx, dx), __fmul_rn(dy, dy)),
                             __fmul_rn(dz, dz));
        bool in = d2 < r2;
        unsigned long long mk = __ballot(in);
        if (!any && mk) { first = base + __builtin_ctzll(mk); any = true; }
        int cb = __builtin_popcountll(mk & ((1ull << lane) - 1ull));
        int slot = taken + cb;
        if (in && slot < NS) gidx[slot] = j;
        taken += (int)__builtin_popcountll(mk);
    }
    if (taken < NS) {
        for (int s = taken + lane; s < NS; s += 64) gidx[s] = any ? first : 0;
    }
    __syncthreads();
    int m0 = (b * NPOINT + i) * NS;
    if (lane < NS) {
        int g = gidx[lane];
        const float* p = xyz + ((size_t)b * N + g) * 3;
        float dx = (p[0] - qx) / radius;
        float dy = (p[1] - qy) / radius;
        float dz = (p[2] - qz) / radius;
        float dist = sqrtf(dx * dx + dy * dy + dz * dz);
        gate[m0 + lane] = 1.f / (1.f + expf(-dist));
    }
    for (int e8 = lane * 8; e8 < NS * CK; e8 += 64 * 8) {
        int s = e8 / CK;
        int c0 = e8 % CK;
        int g = gidx[s];
        const float* frow = feats + (size_t)(b * N + g) * CF;
        const float* prow = xyz + ((size_t)b * N + g) * 3;
        short8 v8;
#pragma unroll
        for (int ii = 0; ii < 8; ++ii) {
            int c = c0 + ii;
            float v;
            if (c < 3) {
                float qc = (c == 0) ? qx : ((c == 1) ? qy : qz);
                v = (prow[c] - qc) / radius;
            } else if (c < 3 + CF) {
                v = frow[c - 3];
            } else {
                v = 0.f;
            }
            v8[ii] = f2b(v);
        }
        *(short8*)(X + (size_t)(m0 + s) * CK + c0) = v8;
    }
}

// ---------------------------------------------------------------- MFMA conv
// R11 structure + coalesced Y epilogue: acc halves staged into LDS
// (stride O+10 shorts, aliases xs) then streamed out 16B/lane contiguous.
template<int CK, int O, bool AFF, bool FUSE>
__global__ __launch_bounds__(256, 3) void mfma_conv(
        const short* __restrict__ X, const short* __restrict__ Whi,
        const short* __restrict__ Wlo, const float* __restrict__ ss,
        short* __restrict__ Y, float* __restrict__ pS, float* __restrict__ pS2,
        const float* __restrict__ qs2, float* __restrict__ q2c) {
    constexpr int KC = CK / 32;
    constexpr int NT = O / 16;
    constexpr int OW = NT / 4;
    constexpr int LR = CK + 8;
    constexpr int LRY = O + 10;          // Y-staging stride (breaks pow2)
    constexpr int CB = CK / 8;
    constexpr int XSZ = (64 * LR > 32 * LRY) ? 64 * LR : 32 * LRY;
    __shared__ __align__(16) short xsbuf[XSZ];
    __shared__ __align__(16) short wh[NT * 512];
    __shared__ __align__(16) short wl[NT * 512];
    __shared__ float ssl[AFF ? 2 * CK : 2];
    __shared__ float sblk[O], s2blk[O];
    static_assert(!FUSE || XSZ * 2 >= 256 * 16 + 128 * 4, "fps LDS fits in xs");
    if constexpr (FUSE) {
        if (blockIdx.x >= CGRID) {
            fps256_body(qs2, q2c, (int)blockIdx.x - CGRID, (char*)xsbuf);
            return;
        }
    }
    short* xs = xsbuf;
    int tid = threadIdx.x;
    int m0 = blockIdx.x * 64;

    if constexpr (AFF) {
        for (int i = tid; i < 2 * CK; i += 256) ssl[i] = ss[i];
        __syncthreads();
    }
    for (int idx = tid; idx < 64 * CB; idx += 256) {
        int r = idx / CB;
        int col = (idx % CB) * 8;
        short8 v = *(const short8*)(X + (size_t)(m0 + r) * CK + col);
        if constexpr (AFF) {
#pragma unroll
            for (int i = 0; i < 8; ++i) {
                float f = b2f(v[i]);
                f = fmaf(f, ssl[col + i], ssl[CK + col + i]);
                f = f > 0.f ? f : 0.2f * f;
                v[i] = f2b(f);
            }
        }
        *(short8*)(xs + r * LR + col) = v;
    }

    int lane = tid & 63;
    int wave = tid >> 6;
    int l15 = lane & 15;
    int quad = lane >> 4;
    int obase = wave * OW * 16;

    f32x4 acc[4][OW];
#pragma unroll
    for (int mt = 0; mt < 4; ++mt)
#pragma unroll
        for (int ot = 0; ot < OW; ++ot) acc[mt][ot] = (f32x4){0.f, 0.f, 0.f, 0.f};

    for (int kc = 0; kc < KC; ++kc) {
        __syncthreads();
        {
            const short8* gH = (const short8*)Whi + (size_t)kc * NT * 64;
            const short8* gL = (const short8*)Wlo + (size_t)kc * NT * 64;
            short8* lH = (short8*)wh;
            short8* lL = (short8*)wl;
            for (int i = tid; i < NT * 64; i += 256) { lH[i] = gH[i]; lL[i] = gL[i]; }
        }
        __syncthreads();
        short8 bf[4];
#pragma unroll
        for (int mt = 0; mt < 4; ++mt)
            bf[mt] = *(const short8*)(xs + (mt * 16 + l15) * LR + kc * 32 + quad * 8);
#pragma unroll
        for (int ot = 0; ot < OW; ++ot) {
            short8 ah = ((const short8*)wh)[(wave * OW + ot) * 64 + lane];
            short8 al = ((const short8*)wl)[(wave * OW + ot) * 64 + lane];
#pragma unroll
            for (int mt = 0; mt < 4; ++mt) {
                acc[mt][ot] = __builtin_amdgcn_mfma_f32_16x16x32_bf16(ah, bf[mt], acc[mt][ot], 0, 0, 0);
                acc[mt][ot] = __builtin_amdgcn_mfma_f32_16x16x32_bf16(al, bf[mt], acc[mt][ot], 0, 0, 0);
            }
        }
    }

    // fused BN stats (block partials, contention-free)
#pragma unroll
    for (int ot = 0; ot < OW; ++ot) {
#pragma unroll
        for (int r4 = 0; r4 < 4; ++r4) {
            float s = 0.f, s2 = 0.f;
#pragma unroll
            for (int mt = 0; mt < 4; ++mt) {
                float v = acc[mt][ot][r4];
                s += v;
                s2 = fmaf(v, v, s2);
            }
            s = dpp_row16_sum(s);
            s2 = dpp_row16_sum(s2);
            if (l15 == 15) {
                int o = obase + ot * 16 + quad * 4 + r4;
                sblk[o] = s;
                s2blk[o] = s2;
            }
        }
    }
    __syncthreads();
    for (int o = tid; o < O; o += 256) {
        pS [(size_t)o * CGRID + blockIdx.x] = sblk[o];
        pS2[(size_t)o * CGRID + blockIdx.x] = s2blk[o];
    }

    // Y write via LDS transpose, two 32-row halves (reuses xs footprint):
    // store path only — values identical to the direct-store epilogue.
    short* ys = xsbuf;
    for (int half = 0; half < 2; ++half) {
        __syncthreads();
#pragma unroll
        for (int mh = 0; mh < 2; ++mh) {
            int mt = half * 2 + mh;
            int r = mh * 16 + l15;
#pragma unroll
            for (int ot = 0; ot < OW; ++ot) {
                short4v pk;
#pragma unroll
                for (int r4 = 0; r4 < 4; ++r4) pk[r4] = f2b(acc[mt][ot][r4]);
                *(short4v*)(ys + r * LRY + obase + ot * 16 + quad * 4) = pk;
            }
        }
        __syncthreads();
        constexpr int CHUNKS = 32 * O / 8;
        for (int i = tid; i < CHUNKS; i += 256) {
            int r = i / (O / 8);
            int col = (i % (O / 8)) * 8;
            *(short8*)(Y + (size_t)(m0 + half * 32 + r) * O + col) =
                *(const short8*)(ys + r * LRY + col);
        }
    }
}

// ---------------------------------------------------------------- BN finalize
template<int O>
__global__ __launch_bounds__(256) void stats_fin(
        const float* __restrict__ pS, const float* __restrict__ pS2,
        const float* __restrict__ gm, const float* __restrict__ bt,
        float* __restrict__ norm) {
    int o = blockIdx.x;
    float s = 0.f, s2 = 0.f;
    for (int p = threadIdx.x; p < CGRID; p += 256) {
        s += pS[(size_t)o * CGRID + p];
        s2 += pS2[(size_t)o * CGRID + p];
    }
#pragma unroll
    for (int off = 32; off >= 1; off >>= 1) {
        s  += __shfl_xor(s,  off, 64);
        s2 += __shfl_xor(s2, off, 64);
    }
    __shared__ float sh[8];
    int wid = threadIdx.x >> 6;
    if ((threadIdx.x & 63) == 0) { sh[wid] = s; sh[4 + wid] = s2; }
    __syncthreads();
    if (threadIdx.x == 0) {
        float S  = sh[0] + sh[1] + sh[2] + sh[3];
        float S2 = sh[4] + sh[5] + sh[6] + sh[7];
        const float invM = 1.f / (float)MCOLS;
        float mu = S * invM;
        float var = S2 * invM - mu * mu;
        float sc = gm[o] * rsqrtf(var + 1e-5f);
        norm[o] = sc;
        norm[O + o] = bt[o] - mu * sc;
    }
}

// stats_fin<64> + shift2: blocks [0,64) finalize conv1a stats; [64,160) shift q1c -> qs2.
__global__ __launch_bounds__(256) void stats_fin64_shift2(
        const float* __restrict__ pS, const float* __restrict__ pS2,
        const float* __restrict__ gm, const float* __restrict__ bt,
        float* __restrict__ norm,
        const float* __restrict__ q1c, float* __restrict__ qs2) {
    constexpr int O = 64;
    if (blockIdx.x >= O) {
        int t = (int)(blockIdx.x - O) * 256 + threadIdx.x;
        if (t < BATCH * 256 * 3) shift_elem(q1c, qs2, t, 256);
        return;
    }
    int o = blockIdx.x;
    float s = 0.f, s2 = 0.f;
    for (int p = threadIdx.x; p < CGRID; p += 256) {
        s += pS[(size_t)o * CGRID + p];
        s2 += pS2[(size_t)o * CGRID + p];
    }
#pragma unroll
    for (int off = 32; off >= 1; off >>= 1) {
        s  += __shfl_xor(s,  off, 64);
        s2 += __shfl_xor(s2, off, 64);
    }
    __shared__ float sh[8];
    int wid = threadIdx.x >> 6;
    if ((threadIdx.x & 63) == 0) { sh[wid] = s; sh[4 + wid] = s2; }
    __syncthreads();
    if (threadIdx.x == 0) {
        float S  = sh[0] + sh[1] + sh[2] + sh[3];
        float S2 = sh[4] + sh[5] + sh[6] + sh[7];
        const float invM = 1.f / (float)MCOLS;
        float mu = S * invM;
        float var = S2 * invM - mu * mu;
        float sc = gm[o] * rsqrtf(var + 1e-5f);
        norm[o] = sc;
        norm[O + o] = bt[o] - mu * sc;
    }
}

// ---------------------------------------------------------------- pool 1
template<int NS, int NPOINT, int O>
__global__ __launch_bounds__(256) void pool1_kernel(
        const short* __restrict__ Y, const float* __restrict__ norm,
        const float* __restrict__ gate, float* __restrict__ out) {
    int t = blockIdx.x * 256 + threadIdx.x;
    int o = t % O;
    int n = (t / O) % NPOINT;
    int b = t / (O * NPOINT);
    int m0 = (b * NPOINT + n) * NS;
    float sc = norm[o], sf = norm[O + o];
    float best = -INFINITY;
#pragma unroll
    for (int k = 0; k < NS; ++k) {
        float v = fmaf(b2f(Y[(size_t)(m0 + k) * O + o]), sc, sf);
        v = v > 0.f ? v : 0.2f * v;
        best = fmaxf(best, gate[m0 + k] * v);
    }
    out[t] = best;
}

// ---------------------------------------------------------------- pool 2
__global__ __launch_bounds__(256) void pool2_kernel(
        const short* __restrict__ Y, const float* __restrict__ norm,
        const float* __restrict__ gate, float* __restrict__ out) {
    constexpr int NS = 32, NPOINT = 128, O = 256;
    int b  = blockIdx.x >> 3;
    int oc = (blockIdx.x >> 1) & 3;
    int nc = blockIdx.x & 1;
    __shared__ float trans[64][65];
    int tid = threadIdx.x;
    for (int w = 0; w < 16; ++w) {
        int idx = w * 256 + tid;
        int o_l = idx & 63;
        int n_l = idx >> 6;
        int o = oc * 64 + o_l;
        int n = nc * 64 + n_l;
        int m0 = (b * NPOINT + n) * NS;
        float sc = norm[o], sf = norm[O + o];
        float best = -INFINITY;
#pragma unroll
        for (int k = 0; k < NS; ++k) {
            float v = fmaf(b2f(Y[(size_t)(m0 + k) * O + o]), sc, sf);
            v = v > 0.f ? v : 0.2f * v;
            best = fmaxf(best, gate[m0 + k] * v);
        }
        trans[o_l][n_l] = best;
    }
    __syncthreads();
    for (int w = 0; w < 16; ++w) {
        int idx = w * 256 + tid;
        int o_l = idx >> 6;
        int n_l = idx & 63;
        out[((size_t)b * O + oc * 64 + o_l) * NPOINT + nc * 64 + n_l] = trans[o_l][n_l];
    }
}

// ---------------------------------------------------------------- launch
extern "C" void kernel_launch(void* const* d_in, const int* in_sizes, int n_in,
                              void* d_out, int out_size, void* d_ws, size_t ws_size,
                              hipStream_t stream) {
    const float* xyz = (const float*)d_in[0];
    const float* w1a = (const float*)d_in[1];
    const float* g1a = (const float*)d_in[2];
    const float* b1a = (const float*)d_in[3];
    const float* w1b = (const float*)d_in[4];
    const float* g1b = (const float*)d_in[5];
    const float* b1b = (const float*)d_in[6];
    const float* w2a = (const float*)d_in[7];
    const float* g2a = (const float*)d_in[8];
    const float* b2a = (const float*)d_in[9];
    const float* w2b = (const float*)d_in[10];
    const float* g2b = (const float*)d_in[11];
    const float* b2b = (const float*)d_in[12];

    char* ws = (char*)d_ws;
    constexpr size_t OFF_Q1C   = 0;          // 98304
    constexpr size_t OFF_GATE1 = 98304;      // 524288
    constexpr size_t OFF_Q2C   = 622592;     // 49152
    constexpr size_t OFF_GATE2 = 671744;     // 524288
    constexpr size_t OFF_NORM  = 1196032;    // 8192
    constexpr size_t OFF_W     = 1204224;    // 294912 -> ends 1499136
    constexpr size_t OFF_PS    = 1499136;    // 2097152
    constexpr size_t OFF_PS2   = 3596288;    // 2097152 -> ends 5693440
    // arenas (lifetime-overlapped):
    // A (32MB): Y1b -> Y2a
    // B (64MB): QS1 -> Y1a -> X2(40MB)+F1(@40MB) -> Y2b
    constexpr size_t OFF_A     = 5693440;    // 33554432
    constexpr size_t OFF_B     = 39247872;   // 67108864 -> ends 106356736
    constexpr size_t OFF_F1    = OFF_B + 41943040;
    constexpr size_t OFF_QS2   = 106356736;  // 98304 dedicated

    float* q1c   = (float*)(ws + OFF_Q1C);
    float* gate1 = (float*)(ws + OFF_GATE1);
    float* q2c   = (float*)(ws + OFF_Q2C);
    float* gate2 = (float*)(ws + OFF_GATE2);
    float* n1a   = (float*)(ws + OFF_NORM);
    float* n1b   = (float*)(ws + OFF_NORM + 512);
    float* n2a   = (float*)(ws + OFF_NORM + 1536);
    float* n2b   = (float*)(ws + OFF_NORM + 2560);
    short* w1bH  = (short*)(ws + OFF_W);
    short* w1bL  = w1bH + 8192;
    short* w2aH  = w1bL + 8192;
    short* w2aL  = w2aH + 20480;
    short* w2bH  = w2aL + 20480;
    short* w2bL  = w2bH + 32768;
    float* pS    = (float*)(ws + OFF_PS);
    float* pS2   = (float*)(ws + OFF_PS2);
    float* qs2   = (float*)(ws + OFF_QS2);

    char* A = ws + OFF_A;
    char* B = ws + OFF_B;
    short* Y1a = (short*)B;
    short* Y1b = (short*)A;
    short* X2  = (short*)B;
    short* Y2a = (short*)A;
    short* Y2b = (short*)B;
    float* qs1 = (float*)B;   // dead after fps1; Y1a overwrites (stream-ordered)
    float* f1  = (float*)(ws + OFF_F1);

    const float r2_1 = (float)(0.15 * 0.15);
    const float r2_2 = (float)(0.3 * 0.3);

    setup_kernel<<<432, 256, 0, stream>>>(w1b, w2a, w2b, xyz, qs1,
                                          w1bH, w1bL, w2aH, w2aL, w2bH, w2bL);

    // ---------------- SA module 1 (N=512 -> 256, ns=16) ----------------
    fps_kernel<512, 256><<<32, 64, 0, stream>>>(qs1, q1c);
    ballq1_conv<512, 256, 16><<<2048, 256, 0, stream>>>(
        xyz, q1c, w1a, r2_1, 0.15f, Y1a, gate1, pS, pS2);
    stats_fin64_shift2<<<160, 256, 0, stream>>>(pS, pS2, g1a, b1a, n1a, q1c, qs2);
    // conv1b + fps2 fused (32 tail blocks run the serial fps2 spine)
    mfma_conv<64, 128, true, true><<<CGRID + 32, 256, 0, stream>>>(
        Y1a, w1bH, w1bL, n1a, Y1b, pS, pS2, qs2, q2c);
    stats_fin<128><<<128, 256, 0, stream>>>(pS, pS2, g1b, b1b, n1b);
    pool1_kernel<16, 256, 128><<<4096, 256, 0, stream>>>(Y1b, n1b, gate1, f1);

    // ---------------- SA module 2 (N=256 -> 128, ns=32) ----------------
    ballq_kernel<256, 128, 32, 128, 160><<<1024, 256, 0, stream>>>(
        q1c, q2c, f1, r2_2, 0.3f, X2, gate2);
    mfma_conv<160, 128, false, false><<<CGRID, 256, 0, stream>>>(
        X2, w2aH, w2aL, nullptr, Y2a, pS, pS2, nullptr, nullptr);
    stats_fin<128><<<128, 256, 0, stream>>>(pS, pS2, g2a, b2a, n2a);
    mfma_conv<128, 256, true, false><<<CGRID, 256, 0, stream>>>(
        Y2a, w2bH, w2bL, n2a, Y2b, pS, pS2, nullptr, nullptr);
    stats_fin<256><<<256, 256, 0, stream>>>(pS, pS2, g2b, b2b, n2b);
    pool2_kernel<<<256, 256, 0, stream>>>(Y2b, n2b, gate2, (float*)d_out);
}

// Round 13
// 371.791 us; speedup vs baseline: 1.0320x; 1.0320x over previous
//
#include <hip/hip_runtime.h>
#include <hip/hip_bf16.h>
#include <math.h>

// MotionNet: PointNet++-style 2-level SA.  B=32, L=16, N=512.
// M = B*npoint*nsample = 131072 for all four conv layers.
//
// R13 == R11 verbatim (best: 373.9 µs).  R12's LDS-transposed conv-Y
// epilogue regressed (+10 µs) — convs are NOT store-transaction-bound; the
// direct D-fragment store is kept.  Structure:
//  - setup kernel: 3x weight prep (fragment-major hi/lo split) + shift1.
//  - fps1: one wave per batch, serial DPP-max spine (latency floor ~83 µs).
//  - ballq1 + conv1a fused: f32 dot product (O=64==wave), BN partials inline.
//  - conv1b (MFMA, split-precision W in LDS per k-chunk) + fps2 fused as 32
//    tail blocks; shift2 fused into stats_fin<64>'s grid.
//  - module 2: ballq (short8 X build) -> conv2a -> conv2b (MFMA) -> pool2.
//  - BN stats: per-block partials pS[o*CGRID+blk] (contention-free) + tiny
//    per-channel finalize kernels.  NEVER same-address atomics (R8: 3x).
// Exactness: FPS argmax + ballquery mask use __fmul_rn/__fadd_rn (no FMA
// contraction) and replicate jnp.argmax first-max / sort-ascending
// semantics exactly.

#define BATCH 32
#define MCOLS 131072
#define CGRID 2048            // MCOLS / 64 conv blocks

typedef __attribute__((ext_vector_type(8))) short short8;
typedef __attribute__((ext_vector_type(4))) short short4v;
typedef __attribute__((ext_vector_type(4))) float f32x4;

__device__ __forceinline__ float b2f(short s) {
    return __uint_as_float(((unsigned)(unsigned short)s) << 16);
}
__device__ __forceinline__ short f2b(float f) {
    __hip_bfloat16 h = __float2bfloat16(f);
    return (short)__builtin_bit_cast(unsigned short, h);
}
__device__ __forceinline__ float dpp_row16_sum(float v) {
    int x;
    x = __builtin_amdgcn_update_dpp(0, __float_as_int(v), 0x111, 0xf, 0xf, true);
    v += __int_as_float(x);
    x = __builtin_amdgcn_update_dpp(0, __float_as_int(v), 0x112, 0xf, 0xf, true);
    v += __int_as_float(x);
    x = __builtin_amdgcn_update_dpp(0, __float_as_int(v), 0x114, 0xf, 0xf, true);
    v += __int_as_float(x);
    x = __builtin_amdgcn_update_dpp(0, __float_as_int(v), 0x118, 0xf, 0xf, true);
    v += __int_as_float(x);
    return v;
}
template<int C>
__device__ __forceinline__ float dpp_max(float v) {
    int x = __builtin_amdgcn_update_dpp(0, __float_as_int(v), C, 0xf, 0xf, true);
    return fmaxf(v, __int_as_float(x));
}
__device__ __forceinline__ float readlane_f(float v, int lane) {
    return __int_as_float(__builtin_amdgcn_readlane(__float_as_int(v), lane));
}

// ---------------------------------------------------------------- setup
__device__ __forceinline__ void prep_elem(const float* __restrict__ w, int O, int C,
                                          int CK, short* __restrict__ hi,
                                          short* __restrict__ lo, int t) {
    if (t >= O * CK) return;
    int o = t / CK, c = t % CK;
    float f = (c < C) ? w[o * C + c] : 0.f;
    short h = f2b(f);
    float fh = b2f(h);
    int NT = O >> 4;
    int ot = o >> 4, l15 = o & 15;
    int kc = c >> 5, quad = (c & 31) >> 3, j = c & 7;
    size_t idx = (((size_t)kc * NT + ot) * 64 + quad * 16 + l15) * 8 + j;
    hi[idx] = h;
    lo[idx] = f2b(f - fh);
}

__device__ __forceinline__ void shift_elem(const float* __restrict__ xyz,
                                           float* __restrict__ qout, int t, int N) {
    int c = t % 3;
    int n = (t / 3) % N;
    int b = t / (3 * N);
    int l = b & 15;
    float v;
    if (l < 15) {
        v = xyz[((size_t)(b + 1) * N + n) * 3 + c];
    } else {
        int g0 = b - 15;
        float acc = 0.f;
        for (int i = 0; i < 15; ++i) {
            float d = __fsub_rn(xyz[((size_t)(g0 + i + 1) * N + n) * 3 + c],
                                xyz[((size_t)(g0 + i) * N + n) * 3 + c]);
            acc = __fadd_rn(acc, d);
        }
        v = __fadd_rn(xyz[((size_t)b * N + n) * 3 + c], __fdiv_rn(acc, 15.f));
    }
    qout[t] = v;
}

// 432 blocks: [0,32) w1b, [32,112) w2a, [112,240) w2b, [240,432) shift1
__global__ __launch_bounds__(256) void setup_kernel(
        const float* __restrict__ w1b, const float* __restrict__ w2a,
        const float* __restrict__ w2b,
        const float* __restrict__ xyz, float* __restrict__ qs1,
        short* w1bH, short* w1bL,
        short* w2aH, short* w2aL, short* w2bH, short* w2bL) {
    int bid = blockIdx.x;
    int tid = threadIdx.x;
    if (bid < 32)       prep_elem(w1b, 128, 64, 64,   w1bH, w1bL, bid * 256 + tid);
    else if (bid < 112) prep_elem(w2a, 128, 131, 160, w2aH, w2aL, (bid - 32) * 256 + tid);
    else if (bid < 240) prep_elem(w2b, 256, 128, 128, w2bH, w2bL, (bid - 112) * 256 + tid);
    else {
        int t = (bid - 240) * 256 + tid;
        if (t < BATCH * 512 * 3) shift_elem(xyz, qs1, t, 512);
    }
}

// ---------------------------------------------------------------- FPS spine
template<int N, int NPOINT>
__device__ __forceinline__ void fps_spine(const float4* __restrict__ qp,
                                          int* __restrict__ sel, int lane) {
    constexpr int P = N / 64;
    float px[P], py[P], pz[P], mind[P];
#pragma unroll
    for (int p = 0; p < P; ++p) {
        float4 v = qp[lane * P + p];
        px[p] = v.x; py[p] = v.y; pz[p] = v.z;
        mind[p] = 1e10f;
    }
    float4 L0 = qp[0];
    float lx = L0.x, ly = L0.y, lz = L0.z;
    for (int s = 1; s < NPOINT; ++s) {
        float mn[P];
#pragma unroll
        for (int p = 0; p < P; ++p) {
            float dx = __fsub_rn(px[p], lx);
            float dy = __fsub_rn(py[p], ly);
            float dz = __fsub_rn(pz[p], lz);
            float d = __fadd_rn(__fadd_rn(__fmul_rn(dx, dx), __fmul_rn(dy, dy)),
                                __fmul_rn(dz, dz));
            float m2 = fminf(mind[p], d);
            mind[p] = m2;
            mn[p] = m2;
        }
        float t[P];
#pragma unroll
        for (int p = 0; p < P; ++p) t[p] = mn[p];
#pragma unroll
        for (int w = P / 2; w >= 1; w >>= 1)
#pragma unroll
            for (int p = 0; p < w; ++p) t[p] = fmaxf(t[p], t[p + w]);
        float local = t[0];
        float m = local;
        m = dpp_max<0x111>(m);
        m = dpp_max<0x112>(m);
        m = dpp_max<0x114>(m);
        m = dpp_max<0x118>(m);
        m = dpp_max<0x142>(m);
        m = dpp_max<0x143>(m);
        float maxd = readlane_f(m, 63);
        int enc = P - 1;
        float bx = px[P - 1], by = py[P - 1], bz = pz[P - 1];
#pragma unroll
        for (int p = P - 2; p >= 0; --p) {
            bool e = (mn[p] == local);
            enc = e ? p : enc;
            bx = e ? px[p] : bx;
            by = e ? py[p] : by;
            bz = e ? pz[p] : bz;
        }
        unsigned long long msk = __ballot(local == maxd);
        int winner = (int)__builtin_ctzll(msk);
        int last = winner * P + __builtin_amdgcn_readlane(enc, winner);
        lx = readlane_f(bx, winner);
        ly = readlane_f(by, winner);
        lz = readlane_f(bz, winner);
        if (lane == 0) sel[s] = last;
    }
}

// Standalone single-wave FPS (fps1).
template<int N, int NPOINT>
__global__ __launch_bounds__(64) void fps_kernel(const float* __restrict__ q,
                                                 float* __restrict__ qsel) {
    int b = blockIdx.x;
    int lane = threadIdx.x;
    __shared__ float4 qp[N];
    __shared__ int sel[NPOINT];
    const float* qb = q + (size_t)b * N * 3;
    for (int j = lane; j < N; j += 64)
        qp[j] = make_float4(qb[j * 3 + 0], qb[j * 3 + 1], qb[j * 3 + 2], 0.f);
    if (lane == 0) sel[0] = 0;
    __syncthreads();
    fps_spine<N, NPOINT>(qp, sel, lane);
    __syncthreads();
    for (int i = lane; i < NPOINT; i += 64) {
        float4 Pt = qp[sel[i]];
        size_t o = ((size_t)b * NPOINT + i) * 3;
        qsel[o + 0] = Pt.x;
        qsel[o + 1] = Pt.y;
        qsel[o + 2] = Pt.z;
    }
}

// 256-thread fps body (fused into conv1b's grid); wave 0 runs the spine.
__device__ void fps256_body(const float* __restrict__ q, float* __restrict__ qsel,
                            int b, char* smem) {
    constexpr int N = 256, NPOINT = 128;
    float4* qp = (float4*)smem;              // 4096 B
    int* sel = (int*)(smem + N * 16);        // 512 B
    int tid = threadIdx.x;
    const float* qb = q + (size_t)b * N * 3;
    for (int j = tid; j < N; j += 256)
        qp[j] = make_float4(qb[j * 3 + 0], qb[j * 3 + 1], qb[j * 3 + 2], 0.f);
    if (tid == 0) sel[0] = 0;
    __syncthreads();
    if (tid < 64) fps_spine<N, NPOINT>(qp, sel, tid);
    __syncthreads();
    for (int i = tid; i < NPOINT; i += 256) {
        float4 Pt = qp[sel[i]];
        size_t o = ((size_t)b * NPOINT + i) * 3;
        qsel[o + 0] = Pt.x;
        qsel[o + 1] = Pt.y;
        qsel[o + 2] = Pt.z;
    }
}

// ---------------------------------------------------------------- ballq1+conv1a
template<int N, int NPOINT, int NS>
__global__ __launch_bounds__(256) void ballq1_conv(
        const float* __restrict__ xyz,    // (B,N,3)
        const float* __restrict__ qpts,   // (B,NPOINT,3)
        const float* __restrict__ w1a,    // (64,6) f32
        float r2, float radius,
        short* __restrict__ Y, float* __restrict__ gate,
        float* __restrict__ pS, float* __restrict__ pS2) {
    static_assert((NS & (NS - 1)) == 0, "NS pow2");
    constexpr int O = 64;
    int tid = threadIdx.x;
    int lane = tid & 63;
    int wib = tid >> 6;
    int wid = blockIdx.x * 4 + wib;
    int b = wid / NPOINT;
    int i = wid % NPOINT;
    const float* qp = qpts + ((size_t)b * NPOINT + i) * 3;
    float qx = qp[0], qy = qp[1], qz = qp[2];
    __shared__ int gsh[4][NS];
    __shared__ float xsh[4][NS][6];
    __shared__ float wsh[O * 6];
    __shared__ float sblk[4][O], s2blk[4][O];
    for (int k = tid; k < O * 6; k += 256) wsh[k] = w1a[k];
    int* gidx = gsh[wib];
    int taken = 0, first = 0;
    bool any = false;
#pragma unroll
    for (int base = 0; base < N; base += 64) {
        int j = base + lane;
        const float* p = xyz + ((size_t)b * N + j) * 3;
        float dx = __fsub_rn(qx, p[0]);
        float dy = __fsub_rn(qy, p[1]);
        float dz = __fsub_rn(qz, p[2]);
        float d2 = __fadd_rn(__fadd_rn(__fmul_rn(dx, dx), __fmul_rn(dy, dy)),
                             __fmul_rn(dz, dz));
        bool in = d2 < r2;
        unsigned long long mk = __ballot(in);
        if (!any && mk) { first = base + __builtin_ctzll(mk); any = true; }
        int cb = __builtin_popcountll(mk & ((1ull << lane) - 1ull));
        int slot = taken + cb;
        if (in && slot < NS) gidx[slot] = j;
        taken += (int)__builtin_popcountll(mk);
    }
    if (taken < NS) {
        for (int s = taken + lane; s < NS; s += 64) gidx[s] = any ? first : 0;
    }
    __syncthreads();   // gidx + wsh visible
    int m0 = wid * NS;
    if (lane < NS) {
        int g = gidx[lane];
        const float* p = xyz + ((size_t)b * N + g) * 3;
        float dx = (p[0] - qx) / radius;
        float dy = (p[1] - qy) / radius;
        float dz = (p[2] - qz) / radius;
        float dist = sqrtf(dx * dx + dy * dy + dz * dz);
        gate[m0 + lane] = 1.f / (1.f + expf(-dist));
        xsh[wib][lane][0] = dx;
        xsh[wib][lane][1] = dy;
        xsh[wib][lane][2] = dz;
        xsh[wib][lane][3] = p[0];
        xsh[wib][lane][4] = p[1];
        xsh[wib][lane][5] = p[2];
    }
    __syncthreads();   // xsh visible (uniform barrier)
    float w0 = wsh[lane * 6 + 0], w1 = wsh[lane * 6 + 1], w2 = wsh[lane * 6 + 2];
    float w3 = wsh[lane * 6 + 3], w4 = wsh[lane * 6 + 4], w5 = wsh[lane * 6 + 5];
    float sum = 0.f, sum2 = 0.f;
#pragma unroll
    for (int s = 0; s < NS; ++s) {
        const float* x = xsh[wib][s];
        float y = fmaf(x[5], w5, fmaf(x[4], w4, fmaf(x[3], w3,
                  fmaf(x[2], w2, fmaf(x[1], w1, x[0] * w0)))));
        Y[(size_t)(m0 + s) * O + lane] = f2b(y);
        sum += y;
        sum2 = fmaf(y, y, sum2);
    }
    sblk[wib][lane] = sum;
    s2blk[wib][lane] = sum2;
    __syncthreads();
    if (tid < O) {
        float S  = sblk[0][tid] + sblk[1][tid] + sblk[2][tid] + sblk[3][tid];
        float S2 = s2blk[0][tid] + s2blk[1][tid] + s2blk[2][tid] + s2blk[3][tid];
        pS [(size_t)tid * CGRID + blockIdx.x] = S;
        pS2[(size_t)tid * CGRID + blockIdx.x] = S2;
    }
}

// ---------------------------------------------------------------- ball query (module 2)
template<int N, int NPOINT, int NS, int CF, int CK>
__global__ __launch_bounds__(256) void ballq_kernel(
        const float* __restrict__ xyz,    // (B,N,3)
        const float* __restrict__ qpts,   // (B,NPOINT,3)
        const float* __restrict__ feats,  // (B,N,CF)
        float r2, float radius,
        short* __restrict__ X, float* __restrict__ gate) {
    static_assert((NS & (NS - 1)) == 0, "NS pow2");
    static_assert(CK % 8 == 0, "CK mult of 8");
    int lane = threadIdx.x & 63;
    int wib = threadIdx.x >> 6;
    int wid = blockIdx.x * 4 + wib;
    int b = wid / NPOINT;
    int i = wid % NPOINT;
    const float* qp = qpts + ((size_t)b * NPOINT + i) * 3;
    float qx = qp[0], qy = qp[1], qz = qp[2];
    __shared__ int gsh[4][NS];
    int* gidx = gsh[wib];
    int taken = 0, first = 0;
    bool any = false;
#pragma unroll
    for (int base = 0; base < N; base += 64) {
        int j = base + lane;
        const float* p = xyz + ((size_t)b * N + j) * 3;
        float dx = __fsub_rn(qx, p[0]);
        float dy = __fsub_rn(qy, p[1]);
        float dz = __fsub_rn(qz, p[2]);
        float d2 = __fadd_rn(__fadd_rn(__fmul_rn(dx, dx), __fmul_rn(dy, dy)),
                             __fmul_rn(dz, dz));
        bool in = d2 < r2;
        unsigned long long mk = __ballot(in);
        if (!any && mk) { first = base + __builtin_ctzll(mk); any = true; }
        int cb = __builtin_popcountll(mk & ((1ull << lane) - 1ull));
        int slot = taken + cb;
        if (in && slot < NS) gidx[slot] = j;
        taken += (int)__builtin_popcountll(mk);
    }
    if (taken < NS) {
        for (int s = taken + lane; s < NS; s += 64) gidx[s] = any ? first : 0;
    }
    __syncthreads();
    int m0 = (b * NPOINT + i) * NS;
    if (lane < NS) {
        int g = gidx[lane];
        const float* p = xyz + ((size_t)b * N + g) * 3;
        float dx = (p[0] - qx) / radius;
        float dy = (p[1] - qy) / radius;
        float dz = (p[2] - qz) / radius;
        float dist = sqrtf(dx * dx + dy * dy + dz * dz);
        gate[m0 + lane] = 1.f / (1.f + expf(-dist));
    }
    for (int e8 = lane * 8; e8 < NS * CK; e8 += 64 * 8) {
        int s = e8 / CK;
        int c0 = e8 % CK;
        int g = gidx[s];
        const float* frow = feats + (size_t)(b * N + g) * CF;
        const float* prow = xyz + ((size_t)b * N + g) * 3;
        short8 v8;
#pragma unroll
        for (int ii = 0; ii < 8; ++ii) {
            int c = c0 + ii;
            float v;
            if (c < 3) {
                float qc = (c == 0) ? qx : ((c == 1) ? qy : qz);
                v = (prow[c] - qc) / radius;
            } else if (c < 3 + CF) {
                v = frow[c - 3];
            } else {
                v = 0.f;
            }
            v8[ii] = f2b(v);
        }
        *(short8*)(X + (size_t)(m0 + s) * CK + c0) = v8;
    }
}

// ---------------------------------------------------------------- MFMA conv
template<int CK, int O, bool AFF, bool FUSE>
__global__ __launch_bounds__(256, 3) void mfma_conv(
        const short* __restrict__ X, const short* __restrict__ Whi,
        const short* __restrict__ Wlo, const float* __restrict__ ss,
        short* __restrict__ Y, float* __restrict__ pS, float* __restrict__ pS2,
        const float* __restrict__ qs2, float* __restrict__ q2c) {
    constexpr int KC = CK / 32;
    constexpr int NT = O / 16;
    constexpr int OW = NT / 4;
    constexpr int LR = CK + 8;
    constexpr int CB = CK / 8;
    __shared__ __align__(16) short xs[64 * LR];
    __shared__ __align__(16) short wh[NT * 512];
    __shared__ __align__(16) short wl[NT * 512];
    __shared__ float ssl[AFF ? 2 * CK : 2];
    __shared__ float sblk[O], s2blk[O];
    static_assert(!FUSE || 64 * LR * 2 >= 256 * 16 + 128 * 4, "fps LDS fits in xs");
    if constexpr (FUSE) {
        if (blockIdx.x >= CGRID) {
            fps256_body(qs2, q2c, (int)blockIdx.x - CGRID, (char*)xs);
            return;
        }
    }
    int tid = threadIdx.x;
    int m0 = blockIdx.x * 64;

    if constexpr (AFF) {
        for (int i = tid; i < 2 * CK; i += 256) ssl[i] = ss[i];
        __syncthreads();
    }
    for (int idx = tid; idx < 64 * CB; idx += 256) {
        int r = idx / CB;
        int col = (idx % CB) * 8;
        short8 v = *(const short8*)(X + (size_t)(m0 + r) * CK + col);
        if constexpr (AFF) {
#pragma unroll
            for (int i = 0; i < 8; ++i) {
                float f = b2f(v[i]);
                f = fmaf(f, ssl[col + i], ssl[CK + col + i]);
                f = f > 0.f ? f : 0.2f * f;
                v[i] = f2b(f);
            }
        }
        *(short8*)(xs + r * LR + col) = v;
    }

    int lane = tid & 63;
    int wave = tid >> 6;
    int l15 = lane & 15;
    int quad = lane >> 4;
    int obase = wave * OW * 16;

    f32x4 acc[4][OW];
#pragma unroll
    for (int mt = 0; mt < 4; ++mt)
#pragma unroll
        for (int ot = 0; ot < OW; ++ot) acc[mt][ot] = (f32x4){0.f, 0.f, 0.f, 0.f};

    for (int kc = 0; kc < KC; ++kc) {
        __syncthreads();
        {
            const short8* gH = (const short8*)Whi + (size_t)kc * NT * 64;
            const short8* gL = (const short8*)Wlo + (size_t)kc * NT * 64;
            short8* lH = (short8*)wh;
            short8* lL = (short8*)wl;
            for (int i = tid; i < NT * 64; i += 256) { lH[i] = gH[i]; lL[i] = gL[i]; }
        }
        __syncthreads();
        short8 bf[4];
#pragma unroll
        for (int mt = 0; mt < 4; ++mt)
            bf[mt] = *(const short8*)(xs + (mt * 16 + l15) * LR + kc * 32 + quad * 8);
#pragma unroll
        for (int ot = 0; ot < OW; ++ot) {
            short8 ah = ((const short8*)wh)[(wave * OW + ot) * 64 + lane];
            short8 al = ((const short8*)wl)[(wave * OW + ot) * 64 + lane];
#pragma unroll
            for (int mt = 0; mt < 4; ++mt) {
                acc[mt][ot] = __builtin_amdgcn_mfma_f32_16x16x32_bf16(ah, bf[mt], acc[mt][ot], 0, 0, 0);
                acc[mt][ot] = __builtin_amdgcn_mfma_f32_16x16x32_bf16(al, bf[mt], acc[mt][ot], 0, 0, 0);
            }
        }
    }

#pragma unroll
    for (int mt = 0; mt < 4; ++mt) {
        size_t ybase = (size_t)(m0 + mt * 16 + l15) * O + obase + quad * 4;
#pragma unroll
        for (int ot = 0; ot < OW; ++ot) {
            short4v pk;
#pragma unroll
            for (int r4 = 0; r4 < 4; ++r4) pk[r4] = f2b(acc[mt][ot][r4]);
            *(short4v*)(Y + ybase + ot * 16) = pk;
        }
    }
#pragma unroll
    for (int ot = 0; ot < OW; ++ot) {
#pragma unroll
        for (int r4 = 0; r4 < 4; ++r4) {
            float s = 0.f, s2 = 0.f;
#pragma unroll
            for (int mt = 0; mt < 4; ++mt) {
                float v = acc[mt][ot][r4];
                s += v;
                s2 = fmaf(v, v, s2);
            }
            s = dpp_row16_sum(s);
            s2 = dpp_row16_sum(s2);
            if (l15 == 15) {
                int o = obase + ot * 16 + quad * 4 + r4;
                sblk[o] = s;
                s2blk[o] = s2;
            }
        }
    }
    __syncthreads();
    for (int o = tid; o < O; o += 256) {
        pS [(size_t)o * CGRID + blockIdx.x] = sblk[o];
        pS2[(size_t)o * CGRID + blockIdx.x] = s2blk[o];
    }
}

// ---------------------------------------------------------------- BN finalize
template<int O>
__global__ __launch_bounds__(256) void stats_fin(
        const float* __restrict__ pS, const float* __restrict__ pS2,
        const float* __restrict__ gm, const float* __restrict__ bt,
        float* __restrict__ norm) {
    int o = blockIdx.x;
    float s = 0.f, s2 = 0.f;
    for (int p = threadIdx.x; p < CGRID; p += 256) {
        s += pS[(size_t)o * CGRID + p];
        s2 += pS2[(size_t)o * CGRID + p];
    }
#pragma unroll
    for (int off = 32; off >= 1; off >>= 1) {
        s  += __shfl_xor(s,  off, 64);
        s2 += __shfl_xor(s2, off, 64);
    }
    __shared__ float sh[8];
    int wid = threadIdx.x >> 6;
    if ((threadIdx.x & 63) == 0) { sh[wid] = s; sh[4 + wid] = s2; }
    __syncthreads();
    if (threadIdx.x == 0) {
        float S  = sh[0] + sh[1] + sh[2] + sh[3];
        float S2 = sh[4] + sh[5] + sh[6] + sh[7];
        const float invM = 1.f / (float)MCOLS;
        float mu = S * invM;
        float var = S2 * invM - mu * mu;
        float sc = gm[o] * rsqrtf(var + 1e-5f);
        norm[o] = sc;
        norm[O + o] = bt[o] - mu * sc;
    }
}

// stats_fin<64> + shift2: blocks [0,64) finalize conv1a stats; [64,160) shift q1c -> qs2.
__global__ __launch_bounds__(256) void stats_fin64_shift2(
        const float* __restrict__ pS, const float* __restrict__ pS2,
        const float* __restrict__ gm, const float* __restrict__ bt,
        float* __restrict__ norm,
        const float* __restrict__ q1c, float* __restrict__ qs2) {
    constexpr int O = 64;
    if (blockIdx.x >= O) {
        int t = (int)(blockIdx.x - O) * 256 + threadIdx.x;
        if (t < BATCH * 256 * 3) shift_elem(q1c, qs2, t, 256);
        return;
    }
    int o = blockIdx.x;
    float s = 0.f, s2 = 0.f;
    for (int p = threadIdx.x; p < CGRID; p += 256) {
        s += pS[(size_t)o * CGRID + p];
        s2 += pS2[(size_t)o * CGRID + p];
    }
#pragma unroll
    for (int off = 32; off >= 1; off >>= 1) {
        s  += __shfl_xor(s,  off, 64);
        s2 += __shfl_xor(s2, off, 64);
    }
    __shared__ float sh[8];
    int wid = threadIdx.x >> 6;
    if ((threadIdx.x & 63) == 0) { sh[wid] = s; sh[4 + wid] = s2; }
    __syncthreads();
    if (threadIdx.x == 0) {
        float S  = sh[0] + sh[1] + sh[2] + sh[3];
        float S2 = sh[4] + sh[5] + sh[6] + sh[7];
        const float invM = 1.f / (float)MCOLS;
        float mu = S * invM;
        float var = S2 * invM - mu * mu;
        float sc = gm[o] * rsqrtf(var + 1e-5f);
        norm[o] = sc;
        norm[O + o] = bt[o] - mu * sc;
    }
}

// ---------------------------------------------------------------- pool 1
template<int NS, int NPOINT, int O>
__global__ __launch_bounds__(256) void pool1_kernel(
        const short* __restrict__ Y, const float* __restrict__ norm,
        const float* __restrict__ gate, float* __restrict__ out) {
    int t = blockIdx.x * 256 + threadIdx.x;
    int o = t % O;
    int n = (t / O) % NPOINT;
    int b = t / (O * NPOINT);
    int m0 = (b * NPOINT + n) * NS;
    float sc = norm[o], sf = norm[O + o];
    float best = -INFINITY;
#pragma unroll
    for (int k = 0; k < NS; ++k) {
        float v = fmaf(b2f(Y[(size_t)(m0 + k) * O + o]), sc, sf);
        v = v > 0.f ? v : 0.2f * v;
        best = fmaxf(best, gate[m0 + k] * v);
    }
    out[t] = best;
}

// ---------------------------------------------------------------- pool 2
__global__ __launch_bounds__(256) void pool2_kernel(
        const short* __restrict__ Y, const float* __restrict__ norm,
        const float* __restrict__ gate, float* __restrict__ out) {
    constexpr int NS = 32, NPOINT = 128, O = 256;
    int b  = blockIdx.x >> 3;
    int oc = (blockIdx.x >> 1) & 3;
    int nc = blockIdx.x & 1;
    __shared__ float trans[64][65];
    int tid = threadIdx.x;
    for (int w = 0; w < 16; ++w) {
        int idx = w * 256 + tid;
        int o_l = idx & 63;
        int n_l = idx >> 6;
        int o = oc * 64 + o_l;
        int n = nc * 64 + n_l;
        int m0 = (b * NPOINT + n) * NS;
        float sc = norm[o], sf = norm[O + o];
        float best = -INFINITY;
#pragma unroll
        for (int k = 0; k < NS; ++k) {
            float v = fmaf(b2f(Y[(size_t)(m0 + k) * O + o]), sc, sf);
            v = v > 0.f ? v : 0.2f * v;
            best = fmaxf(best, gate[m0 + k] * v);
        }
        trans[o_l][n_l] = best;
    }
    __syncthreads();
    for (int w = 0; w < 16; ++w) {
        int idx = w * 256 + tid;
        int o_l = idx >> 6;
        int n_l = idx & 63;
        out[((size_t)b * O + oc * 64 + o_l) * NPOINT + nc * 64 + n_l] = trans[o_l][n_l];
    }
}

// ---------------------------------------------------------------- launch
extern "C" void kernel_launch(void* const* d_in, const int* in_sizes, int n_in,
                              void* d_out, int out_size, void* d_ws, size_t ws_size,
                              hipStream_t stream) {
    const float* xyz = (const float*)d_in[0];
    const float* w1a = (const float*)d_in[1];
    const float* g1a = (const float*)d_in[2];
    const float* b1a = (const float*)d_in[3];
    const float* w1b = (const float*)d_in[4];
    const float* g1b = (const float*)d_in[5];
    const float* b1b = (const float*)d_in[6];
    const float* w2a = (const float*)d_in[7];
    const float* g2a = (const float*)d_in[8];
    const float* b2a = (const float*)d_in[9];
    const float* w2b = (const float*)d_in[10];
    const float* g2b = (const float*)d_in[11];
    const float* b2b = (const float*)d_in[12];

    char* ws = (char*)d_ws;
    constexpr size_t OFF_Q1C   = 0;          // 98304
    constexpr size_t OFF_GATE1 = 98304;      // 524288
    constexpr size_t OFF_Q2C   = 622592;     // 49152
    constexpr size_t OFF_GATE2 = 671744;     // 524288
    constexpr size_t OFF_NORM  = 1196032;    // 8192
    constexpr size_t OFF_W     = 1204224;    // 294912 -> ends 1499136
    constexpr size_t OFF_PS    = 1499136;    // 2097152
    constexpr size_t OFF_PS2   = 3596288;    // 2097152 -> ends 5693440
    // arenas (lifetime-overlapped):
    // A (32MB): Y1b -> Y2a
    // B (64MB): QS1 -> Y1a -> X2(40MB)+F1(@40MB) -> Y2b
    constexpr size_t OFF_A     = 5693440;    // 33554432
    constexpr size_t OFF_B     = 39247872;   // 67108864 -> ends 106356736
    constexpr size_t OFF_F1    = OFF_B + 41943040;
    constexpr size_t OFF_QS2   = 106356736;  // 98304 dedicated

    float* q1c   = (float*)(ws + OFF_Q1C);
    float* gate1 = (float*)(ws + OFF_GATE1);
    float* q2c   = (float*)(ws + OFF_Q2C);
    float* gate2 = (float*)(ws + OFF_GATE2);
    float* n1a   = (float*)(ws + OFF_NORM);
    float* n1b   = (float*)(ws + OFF_NORM + 512);
    float* n2a   = (float*)(ws + OFF_NORM + 1536);
    float* n2b   = (float*)(ws + OFF_NORM + 2560);
    short* w1bH  = (short*)(ws + OFF_W);
    short* w1bL  = w1bH + 8192;
    short* w2aH  = w1bL + 8192;
    short* w2aL  = w2aH + 20480;
    short* w2bH  = w2aL + 20480;
    short* w2bL  = w2bH + 32768;
    float* pS    = (float*)(ws + OFF_PS);
    float* pS2   = (float*)(ws + OFF_PS2);
    float* qs2   = (float*)(ws + OFF_QS2);

    char* A = ws + OFF_A;
    char* B = ws + OFF_B;
    short* Y1a = (short*)B;
    short* Y1b = (short*)A;
    short* X2  = (short*)B;
    short* Y2a = (short*)A;
    short* Y2b = (short*)B;
    float* qs1 = (float*)B;   // dead after fps1; Y1a overwrites (stream-ordered)
    float* f1  = (float*)(ws + OFF_F1);

    const float r2_1 = (float)(0.15 * 0.15);
    const float r2_2 = (float)(0.3 * 0.3);

    setup_kernel<<<432, 256, 0, stream>>>(w1b, w2a, w2b, xyz, qs1,
                                          w1bH, w1bL, w2aH, w2aL, w2bH, w2bL);

    // ---------------- SA module 1 (N=512 -> 256, ns=16) ----------------
    fps_kernel<512, 256><<<32, 64, 0, stream>>>(qs1, q1c);
    ballq1_conv<512, 256, 16><<<2048, 256, 0, stream>>>(
        xyz, q1c, w1a, r2_1, 0.15f, Y1a, gate1, pS, pS2);
    stats_fin64_shift2<<<160, 256, 0, stream>>>(pS, pS2, g1a, b1a, n1a, q1c, qs2);
    // conv1b + fps2 fused (32 tail blocks run the serial fps2 spine)
    mfma_conv<64, 128, true, true><<<CGRID + 32, 256, 0, stream>>>(
        Y1a, w1bH, w1bL, n1a, Y1b, pS, pS2, qs2, q2c);
    stats_fin<128><<<128, 256, 0, stream>>>(pS, pS2, g1b, b1b, n1b);
    pool1_kernel<16, 256, 128><<<4096, 256, 0, stream>>>(Y1b, n1b, gate1, f1);

    // ---------------- SA module 2 (N=256 -> 128, ns=32) ----------------
    ballq_kernel<256, 128, 32, 128, 160><<<1024, 256, 0, stream>>>(
        q1c, q2c, f1, r2_2, 0.3f, X2, gate2);
    mfma_conv<160, 128, false, false><<<CGRID, 256, 0, stream>>>(
        X2, w2aH, w2aL, nullptr, Y2a, pS, pS2, nullptr, nullptr);
    stats_fin<128><<<128, 256, 0, stream>>>(pS, pS2, g2a, b2a, n2a);
    mfma_conv<128, 256, true, false><<<CGRID, 256, 0, stream>>>(
        Y2a, w2bH, w2bL, n2a, Y2b, pS, pS2, nullptr, nullptr);
    stats_fin<256><<<256, 256, 0, stream>>>(pS, pS2, g2b, b2b, n2b);
    pool2_kernel<<<256, 256, 0, stream>>>(Y2b, n2b, gate2, (float*)d_out);
}